// Round 7
// baseline (199.249 us; speedup 1.0000x reference)
//
#include <hip/hip_runtime.h>
#include <stdint.h>

// Fused attention head: out = softmax(mask((Tgt@Wq)(Src@Wk)^T * H^-0.5)) @ (Src@Wv)
// B=4096, T=128, C=128, H=64. One block/batch, 512 threads (8 waves).
// R7 = R6 with the shuffle-redistribution bug fixed: __shfl returns the SOURCE
// lane's value of the named register, so the hi/lo word-pair selection must be
// pulled-both + consumer-side select (R6 pre-selected on the consumer -> wrong).

typedef uint32_t u32x2 __attribute__((ext_vector_type(2)));
typedef uint32_t u32x4 __attribute__((ext_vector_type(4)));
typedef float    f32x4 __attribute__((ext_vector_type(4)));
typedef __bf16   bf16x8 __attribute__((ext_vector_type(8)));

static __device__ __forceinline__ uint32_t pack2(float a, float b) {  // RNE, HW-proven R1/R5
  uint32_t ua = __builtin_bit_cast(uint32_t, a);
  uint32_t ub = __builtin_bit_cast(uint32_t, b);
  ua += 0x7FFFu + ((ua >> 16) & 1u);
  ub += 0x7FFFu + ((ub >> 16) & 1u);
  return (ua >> 16) | (ub & 0xFFFF0000u);
}
static __device__ __forceinline__ f32x4 mfma16(u32x4 a, u32x4 b, f32x4 c) {
  return __builtin_amdgcn_mfma_f32_16x16x32_bf16(
      __builtin_bit_cast(bf16x8, a), __builtin_bit_cast(bf16x8, b), c, 0, 0, 0);
}

// ---- prep: pack Wq/Wk/Wv into MFMA frag layout in ws; detect mask dtype ----
// frag f=(m*4+ct)*4+ks, lane l: 8 bf16 of W[c][h], h=ct*16+(l&15), c=ks*32+(l>>4)*8+0..7.
// Serves BOTH as B-frag of W (V proj) and A-frag of W^T (K/Q proj).
__global__ void prep_w(const float* __restrict__ Wq, const float* __restrict__ Wk,
                       const float* __restrict__ Wv, const void* __restrict__ mask,
                       uint32_t* __restrict__ ws) {
  const int blk = blockIdx.x;
  const int l = threadIdx.x;  // 0..63
  if (blk < 48) {
    const int m  = blk >> 4;
    const int ct = (blk >> 2) & 3;
    const int ks = blk & 3;
    const float* W = (m == 0) ? Wq : ((m == 1) ? Wk : Wv);
    const int h  = ct * 16 + (l & 15);
    const int c0 = ks * 32 + (l >> 4) * 8;
    u32x4 v;
#pragma unroll
    for (int p = 0; p < 4; ++p)
      v[p] = pack2(W[(c0 + 2 * p) * 64 + h], W[(c0 + 2 * p + 1) * 64 + h]);
    ((u32x4*)ws)[blk * 64 + l] = v;
  } else {
    // mask dtype detect: 0=int32(0/1), 1=bytes, 2=float
    const uint32_t* mw = (const uint32_t*)mask;
    int fl = 0;
    for (int i = l * 16; i < l * 16 + 16; ++i) {
      uint32_t x = mw[i];
      if (x == 0x3F800000u) fl = 2;
      else if (x > 1u && fl != 2) fl = 1;
    }
#pragma unroll
    for (int off = 32; off > 0; off >>= 1) {
      int o = __shfl_down(fl, off);
      fl = (o > fl) ? o : fl;
    }
    if (l == 0) ws[12288] = (uint32_t)fl;
  }
}

// LDS (48.5 KB -> 3 blocks/CU):
//  EMB [64][128] bf16 swz (16K)  staging (4 halves, reused)
//  Kb  [128][64] bf16 swz (16K)  K[s][h]
//  Vb  [64][128] bf16 swz (16K)  V^T[h][s]
//  BIAS[128] f32
// Swizzle: 16B chunk c of row r stored at chunk (c ^ (r&7)).
__global__ __launch_bounds__(512, 6) void attn_fused(
    const float* __restrict__ src, const float* __restrict__ tgt,
    const void* __restrict__ mask, const uint32_t* __restrict__ ws,
    float* __restrict__ out) {
  __shared__ __align__(16) uint8_t lds[49664];
  uint8_t* const EMB = lds;
  uint8_t* const Kb  = lds + 16384;
  uint8_t* const Vb  = lds + 32768;
  float*  const BIAS = (float*)(lds + 49152);

  const int b   = blockIdx.x;
  const int tid = (int)threadIdx.x;
  const int l   = tid & 63;
  const int w   = tid >> 6;      // wave 0..7
  const int l15 = l & 15;
  const int g4  = l >> 4;        // 0..3
  const int ct  = w & 3;         // wave's h-tile for K/V projections
  const int sg  = (w >> 2) * 2;  // wave's first local row-tile for K/V (0 or 2)

  const u32x4* wsv = (const u32x4*)ws;
  const int mflag = (int)ws[12288];
  const float* const srcb = src + (size_t)b * 16384;
  const float* const tgtb = tgt + (size_t)b * 16384;

  u32x4 wk[4], wv[4];
#pragma unroll
  for (int ks = 0; ks < 4; ++ks) {
    wk[ks] = wsv[((4 + ct) * 4 + ks) * 64 + l];   // A-frag of Wk^T
    wv[ks] = wsv[((8 + ct) * 4 + ks) * 64 + l];   // B-frag of Wv
  }

  // staging: thread covers 4 fully-coalesced f32x4 chunks (tid + p*512)
  f32x4 pf[4];
  auto stage_load = [&](const float* gbase) {
#pragma unroll
    for (int p = 0; p < 4; ++p)
      pf[p] = *(const f32x4*)(gbase + tid * 4 + p * 2048);
  };
  auto stage_write = [&]() {
#pragma unroll
    for (int p = 0; p < 4; ++p) {
      const int c   = tid + p * 512;
      const int row = c >> 5;     // 0..63
      const int cc  = c & 31;     // f32x4 chunk within row
      u32x2 d = { pack2(pf[p][0], pf[p][1]), pack2(pf[p][2], pf[p][3]) };
      *(u32x2*)(EMB + (row << 8) + ((((cc >> 1) ^ (row & 7))) << 4) + ((cc & 1) << 3)) = d;
    }
  };

  // K = Src @ Wk (stored K[s][h]) and V = Src @ Wv (stored V^T[h][s]), one half.
  auto projKV = [&](int half) {
#pragma unroll
    for (int i = 0; i < 2; ++i) {
      const int st  = sg + i;            // local 16-row tile 0..3
      const int row = st * 16 + l15;     // EMB row
      f32x4 cK = {0, 0, 0, 0}, cV = {0, 0, 0, 0};
#pragma unroll
      for (int ks = 0; ks < 4; ++ks) {
        u32x4 e = *(const u32x4*)(EMB + (row << 8) + ((((ks * 4 + g4) ^ (row & 7))) << 4));
        cK = mfma16(wk[ks], e, cK);   // C[h][s]
        cV = mfma16(e, wv[ks], cV);   // C[s][h]
      }
      const int s  = half * 64 + st * 16 + l15;       // K: n=s per-lane col
      const int h0 = ct * 16 + g4 * 4;                //    m=h rows (packed pair-write)
      u32x2 dk = { pack2(cK[0], cK[1]), pack2(cK[2], cK[3]) };
      *(u32x2*)(Kb + (s << 7) + ((((h0 >> 3) ^ (s & 7))) << 4) + ((h0 & 7) << 1)) = dk;
      const int s0 = half * 64 + st * 16 + g4 * 4;    // V^T: m=s packed, n=h col
      const int h  = ct * 16 + l15;
      u32x2 dv = { pack2(cV[0], cV[1]), pack2(cV[2], cV[3]) };
      *(u32x2*)(Vb + (h << 8) + ((((s0 >> 3) ^ (h & 7))) << 4) + ((s0 & 7) << 1)) = dv;
    }
  };

  // Consumer-aligned Q projection: wave w computes Q^T C-frags for ITS OWN
  // t-tile (t = 16w + l15), all 64 h (4 ct tiles), Wq A-frags streamed from L2.
  // Lane holds qp[ct*2+p] = bf16x2 of Q^T[h = ct*16 + g4*4 + 2p + {0,1}][t].
  uint32_t qp[8];
  auto projQ_own = [&]() {
    const int row = (w & 3) * 16 + l15;  // EMB row of this wave's t (within half)
    f32x4 c0 = {0,0,0,0}, c1 = {0,0,0,0}, c2 = {0,0,0,0}, c3 = {0,0,0,0};
#pragma unroll
    for (int ks = 0; ks < 4; ++ks) {
      u32x4 e = *(const u32x4*)(EMB + (row << 8) + ((((ks * 4 + g4) ^ (row & 7))) << 4));
      c0 = mfma16(wsv[(0  + ks) * 64 + l], e, c0);
      c1 = mfma16(wsv[(4  + ks) * 64 + l], e, c1);
      c2 = mfma16(wsv[(8  + ks) * 64 + l], e, c2);
      c3 = mfma16(wsv[(12 + ks) * 64 + l], e, c3);
    }
    qp[0] = pack2(c0[0], c0[1]); qp[1] = pack2(c0[2], c0[3]);
    qp[2] = pack2(c1[0], c1[1]); qp[3] = pack2(c1[2], c1[3]);
    qp[4] = pack2(c2[0], c2[1]); qp[5] = pack2(c2[2], c2[3]);
    qp[6] = pack2(c3[0], c3[1]); qp[7] = pack2(c3[2], c3[3]);
  };

  // ---- pipeline: 7 barriers; loads issued one phase early ----
  stage_load(srcb);
  float biasv = 0.0f;
  if (tid < 128) {
    bool valid;
    if (mflag == 1)      valid = ((const uint8_t*)mask)[b * 128 + tid] != 0;
    else if (mflag == 0) valid = ((const int*)mask)[b * 128 + tid] != 0;
    else                 valid = ((const float*)mask)[b * 128 + tid] != 0.0f;
    biasv = valid ? 0.0f : -1e30f;
  }
  stage_write();
  if (tid < 128) BIAS[tid] = biasv;
  __syncthreads();                 // B1
  stage_load(srcb + 8192);
  projKV(0);
  __syncthreads();                 // B2
  stage_write();
  __syncthreads();                 // B3
  stage_load(tgtb);
  projKV(1);
  __syncthreads();                 // B4
  stage_write();
  __syncthreads();                 // B5
  stage_load(tgtb + 8192);         // D loads in flight across B6/B7
  if (w < 4) projQ_own();          // reads EMB(tgt half 0)
  __syncthreads();                 // B6: EMB(C) reads done
  stage_write();
  __syncthreads();                 // B7: EMB(D) ready
  if (w >= 4) projQ_own();         // reads EMB(tgt half 1)
  // ---- no more barriers: free-run tail (Kb/Vb/EMB read-only, P in regs) ----

  // C-frag -> B-frag redistribution. Consumer (g4,l15) word m of step ks needs
  // h(or s) = ks*32 + g4*8 + 2m + {0,1}, held by producer lane
  // (2*(g4&1) + (m>>1))*16 + l15 in word [4ks + 2*(g4>>1) + (m&1)].
  // MUST pull both word-pairs (register name uniform; source evaluates) and
  // select with the consumer's hi2 AFTER the shuffle (R6 bug: selected before).
  const int hi2 = g4 >> 1;
  const int sA  = ((g4 & 1) * 2) * 16 + l15;  // src lane for words m=0,1
  const int sB  = sA + 16;                    // src lane for words m=2,3

  u32x4 qB[2];
#pragma unroll
  for (int ks = 0; ks < 2; ++ks) {
    uint32_t a0 = (uint32_t)__shfl((int)qp[4 * ks + 0], sA);
    uint32_t a1 = (uint32_t)__shfl((int)qp[4 * ks + 1], sA);
    uint32_t a2 = (uint32_t)__shfl((int)qp[4 * ks + 2], sA);
    uint32_t a3 = (uint32_t)__shfl((int)qp[4 * ks + 3], sA);
    uint32_t b0 = (uint32_t)__shfl((int)qp[4 * ks + 0], sB);
    uint32_t b1 = (uint32_t)__shfl((int)qp[4 * ks + 1], sB);
    uint32_t b2 = (uint32_t)__shfl((int)qp[4 * ks + 2], sB);
    uint32_t b3 = (uint32_t)__shfl((int)qp[4 * ks + 3], sB);
    qB[ks][0] = hi2 ? a2 : a0;
    qB[ks][1] = hi2 ? a3 : a1;
    qB[ks][2] = hi2 ? b2 : b0;
    qB[ks][3] = hi2 ? b3 : b1;
  }

  // S^T = K @ Q^T : per lane col t = 16w + l15, rows s = mt*16 + g4*4 + r
  const int tq = 16 * w + l15;
  f32x4 sacc[8];
#pragma unroll
  for (int mt = 0; mt < 8; ++mt) sacc[mt] = {0, 0, 0, 0};
  __builtin_amdgcn_s_setprio(1);
#pragma unroll
  for (int mt = 0; mt < 8; ++mt) {
    const int srow = mt * 16 + l15;
    u32x4 k0 = *(const u32x4*)(Kb + (srow << 7) + (((g4 ^ (srow & 7))) << 4));
    u32x4 k1 = *(const u32x4*)(Kb + (srow << 7) + ((((4 + g4) ^ (srow & 7))) << 4));
    sacc[mt] = mfma16(k0, qB[0], sacc[mt]);
    sacc[mt] = mfma16(k1, qB[1], sacc[mt]);
  }
  __builtin_amdgcn_s_setprio(0);

  // softmax over s (per lane: 32 s-values of row t; reduce across 4-lane group)
  float m = -3.0e38f;
#pragma unroll
  for (int mt = 0; mt < 8; ++mt) {
    f32x4 b4 = *(const f32x4*)(BIAS + mt * 16 + g4 * 4);
#pragma unroll
    for (int r = 0; r < 4; ++r) {
      float v = sacc[mt][r] * 0.125f + b4[r];  // scale = H^-0.5 ; pad bias -1e30
      sacc[mt][r] = v;
      m = fmaxf(m, v);
    }
  }
  m = fmaxf(m, __shfl_xor(m, 16));
  m = fmaxf(m, __shfl_xor(m, 32));
  float sum = 0.0f;
#pragma unroll
  for (int mt = 0; mt < 8; ++mt) {
#pragma unroll
    for (int r = 0; r < 4; ++r) {
      const int s = mt * 16 + g4 * 4 + r;
      float p = __expf(sacc[mt][r] - m);
      p = (s <= tq) ? p : 0.0f;               // causal, multiplicative
      sacc[mt][r] = p;
      sum += p;
    }
  }
  sum += __shfl_xor(sum, 16);
  sum += __shfl_xor(sum, 32);
  const float inv = 1.0f / sum;  // >0: col 0 always valid & causal-visible

  // pack P (unnormalized, <=1): sp[2mt+p] = bf16x2 of P^T[s=mt*16+g4*4+2p+{0,1}][t]
  uint32_t sp[16];
#pragma unroll
  for (int mt = 0; mt < 8; ++mt) {
    sp[2 * mt]     = pack2(sacc[mt][0], sacc[mt][1]);
    sp[2 * mt + 1] = pack2(sacc[mt][2], sacc[mt][3]);
  }

  // OUT^T = V^T @ P^T : A = V^T from Vb rows, B = P via double-pull shuffles
  f32x4 oacc[4];
#pragma unroll
  for (int vt = 0; vt < 4; ++vt) oacc[vt] = {0, 0, 0, 0};
  __builtin_amdgcn_s_setprio(1);
#pragma unroll
  for (int ks = 0; ks < 4; ++ks) {
    uint32_t a0 = (uint32_t)__shfl((int)sp[4 * ks + 0], sA);
    uint32_t a1 = (uint32_t)__shfl((int)sp[4 * ks + 1], sA);
    uint32_t a2 = (uint32_t)__shfl((int)sp[4 * ks + 2], sA);
    uint32_t a3 = (uint32_t)__shfl((int)sp[4 * ks + 3], sA);
    uint32_t b0 = (uint32_t)__shfl((int)sp[4 * ks + 0], sB);
    uint32_t b1 = (uint32_t)__shfl((int)sp[4 * ks + 1], sB);
    uint32_t b2 = (uint32_t)__shfl((int)sp[4 * ks + 2], sB);
    uint32_t b3 = (uint32_t)__shfl((int)sp[4 * ks + 3], sB);
    u32x4 pb;
    pb[0] = hi2 ? a2 : a0;
    pb[1] = hi2 ? a3 : a1;
    pb[2] = hi2 ? b2 : b0;
    pb[3] = hi2 ? b3 : b1;
#pragma unroll
    for (int vt = 0; vt < 4; ++vt) {
      const int vrow = vt * 16 + l15;
      u32x4 vf = *(const u32x4*)(Vb + (vrow << 8) + ((((ks * 4 + g4) ^ (vrow & 7))) << 4));
      oacc[vt] = mfma16(vf, pb, oacc[vt]);
    }
  }
  __builtin_amdgcn_s_setprio(0);

  // epilogue: out[t][h], t = 16w + l15, h = vt*16 + g4*4 + r ; fold 1/sum
  float* const ob = out + (size_t)b * 8192 + (size_t)tq * 64;
#pragma unroll
  for (int vt = 0; vt < 4; ++vt) {
    f32x4 o = { oacc[vt][0] * inv, oacc[vt][1] * inv,
                oacc[vt][2] * inv, oacc[vt][3] * inv };
    *(f32x4*)(ob + vt * 16 + g4 * 4) = o;
  }
}

extern "C" void kernel_launch(void* const* d_in, const int* in_sizes, int n_in,
                              void* d_out, int out_size, void* d_ws, size_t ws_size,
                              hipStream_t stream) {
  const float* src = (const float*)d_in[0];
  const float* tgt = (const float*)d_in[1];
  const void*  msk = d_in[2];
  const float* Wq  = (const float*)d_in[3];
  const float* Wk  = (const float*)d_in[4];
  const float* Wv  = (const float*)d_in[5];
  uint32_t* ws = (uint32_t*)d_ws;  // 48KB W frags + mask-dtype flag
  float* out = (float*)d_out;
  const int B = in_sizes[0] / (128 * 128);

  hipLaunchKernelGGL(prep_w, dim3(49), dim3(64), 0, stream, Wq, Wk, Wv, msk, ws);
  hipLaunchKernelGGL(attn_fused, dim3(B), dim3(512), 0, stream,
                     src, tgt, msk, ws, out);
}

// Round 8
// 167.329 us; speedup vs baseline: 1.1908x; 1.1908x over previous
//
#include <hip/hip_runtime.h>
#include <stdint.h>

// Fused attention head: out = softmax(mask((Tgt@Wq)(Src@Wk)^T * H^-0.5)) @ (Src@Wv)
// B=4096, T=128, C=128, H=64. One block/batch, 512 threads (8 waves).
// R8 = R7 (proven correct) with ONE change: __launch_bounds__(512, 3).
// Empirical finding (R1/R5/R7 VGPR counts 64/56/40): the 2nd launch_bounds arg
// on this toolchain is CUDA-style min-BLOCKS-per-CU (VGPR cap = 2048/(8*arg)).
// R7's arg=6 demanded 48 waves/CU -> cap 40 -> ~200MB scratch spill traffic.
// arg=3 matches the 48.5KB-LDS limit (3 blocks/CU) -> cap ~85 -> no spill.

typedef uint32_t u32x2 __attribute__((ext_vector_type(2)));
typedef uint32_t u32x4 __attribute__((ext_vector_type(4)));
typedef float    f32x4 __attribute__((ext_vector_type(4)));
typedef __bf16   bf16x8 __attribute__((ext_vector_type(8)));

static __device__ __forceinline__ uint32_t pack2(float a, float b) {  // RNE, HW-proven R1/R5
  uint32_t ua = __builtin_bit_cast(uint32_t, a);
  uint32_t ub = __builtin_bit_cast(uint32_t, b);
  ua += 0x7FFFu + ((ua >> 16) & 1u);
  ub += 0x7FFFu + ((ub >> 16) & 1u);
  return (ua >> 16) | (ub & 0xFFFF0000u);
}
static __device__ __forceinline__ f32x4 mfma16(u32x4 a, u32x4 b, f32x4 c) {
  return __builtin_amdgcn_mfma_f32_16x16x32_bf16(
      __builtin_bit_cast(bf16x8, a), __builtin_bit_cast(bf16x8, b), c, 0, 0, 0);
}

// ---- prep: pack Wq/Wk/Wv into MFMA frag layout in ws; detect mask dtype ----
// frag f=(m*4+ct)*4+ks, lane l: 8 bf16 of W[c][h], h=ct*16+(l&15), c=ks*32+(l>>4)*8+0..7.
// Serves BOTH as B-frag of W (V proj) and A-frag of W^T (K/Q proj).
__global__ void prep_w(const float* __restrict__ Wq, const float* __restrict__ Wk,
                       const float* __restrict__ Wv, const void* __restrict__ mask,
                       uint32_t* __restrict__ ws) {
  const int blk = blockIdx.x;
  const int l = threadIdx.x;  // 0..63
  if (blk < 48) {
    const int m  = blk >> 4;
    const int ct = (blk >> 2) & 3;
    const int ks = blk & 3;
    const float* W = (m == 0) ? Wq : ((m == 1) ? Wk : Wv);
    const int h  = ct * 16 + (l & 15);
    const int c0 = ks * 32 + (l >> 4) * 8;
    u32x4 v;
#pragma unroll
    for (int p = 0; p < 4; ++p)
      v[p] = pack2(W[(c0 + 2 * p) * 64 + h], W[(c0 + 2 * p + 1) * 64 + h]);
    ((u32x4*)ws)[blk * 64 + l] = v;
  } else {
    // mask dtype detect: 0=int32(0/1), 1=bytes, 2=float
    const uint32_t* mw = (const uint32_t*)mask;
    int fl = 0;
    for (int i = l * 16; i < l * 16 + 16; ++i) {
      uint32_t x = mw[i];
      if (x == 0x3F800000u) fl = 2;
      else if (x > 1u && fl != 2) fl = 1;
    }
#pragma unroll
    for (int off = 32; off > 0; off >>= 1) {
      int o = __shfl_down(fl, off);
      fl = (o > fl) ? o : fl;
    }
    if (l == 0) ws[12288] = (uint32_t)fl;
  }
}

// LDS (48.5 KB -> 3 blocks/CU):
//  EMB [64][128] bf16 swz (16K)  staging (4 halves, reused)
//  Kb  [128][64] bf16 swz (16K)  K[s][h]
//  Vb  [64][128] bf16 swz (16K)  V^T[h][s]
//  BIAS[128] f32
// Swizzle: 16B chunk c of row r stored at chunk (c ^ (r&7)).
__global__ __launch_bounds__(512, 3) void attn_fused(
    const float* __restrict__ src, const float* __restrict__ tgt,
    const void* __restrict__ mask, const uint32_t* __restrict__ ws,
    float* __restrict__ out) {
  __shared__ __align__(16) uint8_t lds[49664];
  uint8_t* const EMB = lds;
  uint8_t* const Kb  = lds + 16384;
  uint8_t* const Vb  = lds + 32768;
  float*  const BIAS = (float*)(lds + 49152);

  const int b   = blockIdx.x;
  const int tid = (int)threadIdx.x;
  const int l   = tid & 63;
  const int w   = tid >> 6;      // wave 0..7
  const int l15 = l & 15;
  const int g4  = l >> 4;        // 0..3
  const int ct  = w & 3;         // wave's h-tile for K/V projections
  const int sg  = (w >> 2) * 2;  // wave's first local row-tile for K/V (0 or 2)

  const u32x4* wsv = (const u32x4*)ws;
  const int mflag = (int)ws[12288];
  const float* const srcb = src + (size_t)b * 16384;
  const float* const tgtb = tgt + (size_t)b * 16384;

  u32x4 wk[4], wv[4];
#pragma unroll
  for (int ks = 0; ks < 4; ++ks) {
    wk[ks] = wsv[((4 + ct) * 4 + ks) * 64 + l];   // A-frag of Wk^T
    wv[ks] = wsv[((8 + ct) * 4 + ks) * 64 + l];   // B-frag of Wv
  }

  // staging: thread covers 4 fully-coalesced f32x4 chunks (tid + p*512)
  f32x4 pf[4];
  auto stage_load = [&](const float* gbase) {
#pragma unroll
    for (int p = 0; p < 4; ++p)
      pf[p] = *(const f32x4*)(gbase + tid * 4 + p * 2048);
  };
  auto stage_write = [&]() {
#pragma unroll
    for (int p = 0; p < 4; ++p) {
      const int c   = tid + p * 512;
      const int row = c >> 5;     // 0..63
      const int cc  = c & 31;     // f32x4 chunk within row
      u32x2 d = { pack2(pf[p][0], pf[p][1]), pack2(pf[p][2], pf[p][3]) };
      *(u32x2*)(EMB + (row << 8) + ((((cc >> 1) ^ (row & 7))) << 4) + ((cc & 1) << 3)) = d;
    }
  };

  // K = Src @ Wk (stored K[s][h]) and V = Src @ Wv (stored V^T[h][s]), one half.
  auto projKV = [&](int half) {
#pragma unroll
    for (int i = 0; i < 2; ++i) {
      const int st  = sg + i;            // local 16-row tile 0..3
      const int row = st * 16 + l15;     // EMB row
      f32x4 cK = {0, 0, 0, 0}, cV = {0, 0, 0, 0};
#pragma unroll
      for (int ks = 0; ks < 4; ++ks) {
        u32x4 e = *(const u32x4*)(EMB + (row << 8) + ((((ks * 4 + g4) ^ (row & 7))) << 4));
        cK = mfma16(wk[ks], e, cK);   // C[h][s]
        cV = mfma16(e, wv[ks], cV);   // C[s][h]
      }
      const int s  = half * 64 + st * 16 + l15;       // K: n=s per-lane col
      const int h0 = ct * 16 + g4 * 4;                //    m=h rows (packed pair-write)
      u32x2 dk = { pack2(cK[0], cK[1]), pack2(cK[2], cK[3]) };
      *(u32x2*)(Kb + (s << 7) + ((((h0 >> 3) ^ (s & 7))) << 4) + ((h0 & 7) << 1)) = dk;
      const int s0 = half * 64 + st * 16 + g4 * 4;    // V^T: m=s packed, n=h col
      const int h  = ct * 16 + l15;
      u32x2 dv = { pack2(cV[0], cV[1]), pack2(cV[2], cV[3]) };
      *(u32x2*)(Vb + (h << 8) + ((((s0 >> 3) ^ (h & 7))) << 4) + ((s0 & 7) << 1)) = dv;
    }
  };

  // Consumer-aligned Q projection: wave w computes Q^T C-frags for ITS OWN
  // t-tile (t = 16w + l15), all 64 h (4 ct tiles), Wq A-frags streamed from L2.
  // Lane holds qp[ct*2+p] = bf16x2 of Q^T[h = ct*16 + g4*4 + 2p + {0,1}][t].
  uint32_t qp[8];
  auto projQ_own = [&]() {
    const int row = (w & 3) * 16 + l15;  // EMB row of this wave's t (within half)
    f32x4 c0 = {0,0,0,0}, c1 = {0,0,0,0}, c2 = {0,0,0,0}, c3 = {0,0,0,0};
#pragma unroll
    for (int ks = 0; ks < 4; ++ks) {
      u32x4 e = *(const u32x4*)(EMB + (row << 8) + ((((ks * 4 + g4) ^ (row & 7))) << 4));
      c0 = mfma16(wsv[(0  + ks) * 64 + l], e, c0);
      c1 = mfma16(wsv[(4  + ks) * 64 + l], e, c1);
      c2 = mfma16(wsv[(8  + ks) * 64 + l], e, c2);
      c3 = mfma16(wsv[(12 + ks) * 64 + l], e, c3);
    }
    qp[0] = pack2(c0[0], c0[1]); qp[1] = pack2(c0[2], c0[3]);
    qp[2] = pack2(c1[0], c1[1]); qp[3] = pack2(c1[2], c1[3]);
    qp[4] = pack2(c2[0], c2[1]); qp[5] = pack2(c2[2], c2[3]);
    qp[6] = pack2(c3[0], c3[1]); qp[7] = pack2(c3[2], c3[3]);
  };

  // ---- pipeline: 7 barriers; loads issued one phase early ----
  stage_load(srcb);
  float biasv = 0.0f;
  if (tid < 128) {
    bool valid;
    if (mflag == 1)      valid = ((const uint8_t*)mask)[b * 128 + tid] != 0;
    else if (mflag == 0) valid = ((const int*)mask)[b * 128 + tid] != 0;
    else                 valid = ((const float*)mask)[b * 128 + tid] != 0.0f;
    biasv = valid ? 0.0f : -1e30f;
  }
  stage_write();
  if (tid < 128) BIAS[tid] = biasv;
  __syncthreads();                 // B1
  stage_load(srcb + 8192);
  projKV(0);
  __syncthreads();                 // B2
  stage_write();
  __syncthreads();                 // B3
  stage_load(tgtb);
  projKV(1);
  __syncthreads();                 // B4
  stage_write();
  __syncthreads();                 // B5
  stage_load(tgtb + 8192);         // D loads in flight across B6/B7
  if (w < 4) projQ_own();          // reads EMB(tgt half 0)
  __syncthreads();                 // B6: EMB(C) reads done
  stage_write();
  __syncthreads();                 // B7: EMB(D) ready
  if (w >= 4) projQ_own();         // reads EMB(tgt half 1)
  // ---- no more barriers: free-run tail (Kb/Vb/EMB read-only, P in regs) ----

  // C-frag -> B-frag redistribution. Consumer (g4,l15) word m of step ks needs
  // h(or s) = ks*32 + g4*8 + 2m + {0,1}, held by producer lane
  // (2*(g4&1) + (m>>1))*16 + l15 in word [4ks + 2*(g4>>1) + (m&1)].
  // Pull both word-pairs (register name uniform; source lane evaluates) and
  // select with the consumer's hi2 AFTER the shuffle.
  const int hi2 = g4 >> 1;
  const int sA  = ((g4 & 1) * 2) * 16 + l15;  // src lane for words m=0,1
  const int sB  = sA + 16;                    // src lane for words m=2,3

  u32x4 qB[2];
#pragma unroll
  for (int ks = 0; ks < 2; ++ks) {
    uint32_t a0 = (uint32_t)__shfl((int)qp[4 * ks + 0], sA);
    uint32_t a1 = (uint32_t)__shfl((int)qp[4 * ks + 1], sA);
    uint32_t a2 = (uint32_t)__shfl((int)qp[4 * ks + 2], sA);
    uint32_t a3 = (uint32_t)__shfl((int)qp[4 * ks + 3], sA);
    uint32_t b0 = (uint32_t)__shfl((int)qp[4 * ks + 0], sB);
    uint32_t b1 = (uint32_t)__shfl((int)qp[4 * ks + 1], sB);
    uint32_t b2 = (uint32_t)__shfl((int)qp[4 * ks + 2], sB);
    uint32_t b3 = (uint32_t)__shfl((int)qp[4 * ks + 3], sB);
    qB[ks][0] = hi2 ? a2 : a0;
    qB[ks][1] = hi2 ? a3 : a1;
    qB[ks][2] = hi2 ? b2 : b0;
    qB[ks][3] = hi2 ? b3 : b1;
  }

  // S^T = K @ Q^T : per lane col t = 16w + l15, rows s = mt*16 + g4*4 + r
  const int tq = 16 * w + l15;
  f32x4 sacc[8];
#pragma unroll
  for (int mt = 0; mt < 8; ++mt) sacc[mt] = {0, 0, 0, 0};
  __builtin_amdgcn_s_setprio(1);
#pragma unroll
  for (int mt = 0; mt < 8; ++mt) {
    const int srow = mt * 16 + l15;
    u32x4 k0 = *(const u32x4*)(Kb + (srow << 7) + (((g4 ^ (srow & 7))) << 4));
    u32x4 k1 = *(const u32x4*)(Kb + (srow << 7) + ((((4 + g4) ^ (srow & 7))) << 4));
    sacc[mt] = mfma16(k0, qB[0], sacc[mt]);
    sacc[mt] = mfma16(k1, qB[1], sacc[mt]);
  }
  __builtin_amdgcn_s_setprio(0);

  // softmax over s (per lane: 32 s-values of row t; reduce across 4-lane group)
  float m = -3.0e38f;
#pragma unroll
  for (int mt = 0; mt < 8; ++mt) {
    f32x4 b4 = *(const f32x4*)(BIAS + mt * 16 + g4 * 4);
#pragma unroll
    for (int r = 0; r < 4; ++r) {
      float v = sacc[mt][r] * 0.125f + b4[r];  // scale = H^-0.5 ; pad bias -1e30
      sacc[mt][r] = v;
      m = fmaxf(m, v);
    }
  }
  m = fmaxf(m, __shfl_xor(m, 16));
  m = fmaxf(m, __shfl_xor(m, 32));
  float sum = 0.0f;
#pragma unroll
  for (int mt = 0; mt < 8; ++mt) {
#pragma unroll
    for (int r = 0; r < 4; ++r) {
      const int s = mt * 16 + g4 * 4 + r;
      float p = __expf(sacc[mt][r] - m);
      p = (s <= tq) ? p : 0.0f;               // causal, multiplicative
      sacc[mt][r] = p;
      sum += p;
    }
  }
  sum += __shfl_xor(sum, 16);
  sum += __shfl_xor(sum, 32);
  const float inv = 1.0f / sum;  // >0: col 0 always valid & causal-visible

  // pack P (unnormalized, <=1): sp[2mt+p] = bf16x2 of P^T[s=mt*16+g4*4+2p+{0,1}][t]
  uint32_t sp[16];
#pragma unroll
  for (int mt = 0; mt < 8; ++mt) {
    sp[2 * mt]     = pack2(sacc[mt][0], sacc[mt][1]);
    sp[2 * mt + 1] = pack2(sacc[mt][2], sacc[mt][3]);
  }

  // OUT^T = V^T @ P^T : A = V^T from Vb rows, B = P via double-pull shuffles
  f32x4 oacc[4];
#pragma unroll
  for (int vt = 0; vt < 4; ++vt) oacc[vt] = {0, 0, 0, 0};
  __builtin_amdgcn_s_setprio(1);
#pragma unroll
  for (int ks = 0; ks < 4; ++ks) {
    uint32_t a0 = (uint32_t)__shfl((int)sp[4 * ks + 0], sA);
    uint32_t a1 = (uint32_t)__shfl((int)sp[4 * ks + 1], sA);
    uint32_t a2 = (uint32_t)__shfl((int)sp[4 * ks + 2], sA);
    uint32_t a3 = (uint32_t)__shfl((int)sp[4 * ks + 3], sA);
    uint32_t b0 = (uint32_t)__shfl((int)sp[4 * ks + 0], sB);
    uint32_t b1 = (uint32_t)__shfl((int)sp[4 * ks + 1], sB);
    uint32_t b2 = (uint32_t)__shfl((int)sp[4 * ks + 2], sB);
    uint32_t b3 = (uint32_t)__shfl((int)sp[4 * ks + 3], sB);
    u32x4 pb;
    pb[0] = hi2 ? a2 : a0;
    pb[1] = hi2 ? a3 : a1;
    pb[2] = hi2 ? b2 : b0;
    pb[3] = hi2 ? b3 : b1;
#pragma unroll
    for (int vt = 0; vt < 4; ++vt) {
      const int vrow = vt * 16 + l15;
      u32x4 vf = *(const u32x4*)(Vb + (vrow << 8) + ((((ks * 4 + g4) ^ (vrow & 7))) << 4));
      oacc[vt] = mfma16(vf, pb, oacc[vt]);
    }
  }
  __builtin_amdgcn_s_setprio(0);

  // epilogue: out[t][h], t = 16w + l15, h = vt*16 + g4*4 + r ; fold 1/sum
  float* const ob = out + (size_t)b * 8192 + (size_t)tq * 64;
#pragma unroll
  for (int vt = 0; vt < 4; ++vt) {
    f32x4 o = { oacc[vt][0] * inv, oacc[vt][1] * inv,
                oacc[vt][2] * inv, oacc[vt][3] * inv };
    *(f32x4*)(ob + vt * 16 + g4 * 4) = o;
  }
}

extern "C" void kernel_launch(void* const* d_in, const int* in_sizes, int n_in,
                              void* d_out, int out_size, void* d_ws, size_t ws_size,
                              hipStream_t stream) {
  const float* src = (const float*)d_in[0];
  const float* tgt = (const float*)d_in[1];
  const void*  msk = d_in[2];
  const float* Wq  = (const float*)d_in[3];
  const float* Wk  = (const float*)d_in[4];
  const float* Wv  = (const float*)d_in[5];
  uint32_t* ws = (uint32_t*)d_ws;  // 48KB W frags + mask-dtype flag
  float* out = (float*)d_out;
  const int B = in_sizes[0] / (128 * 128);

  hipLaunchKernelGGL(prep_w, dim3(49), dim3(64), 0, stream, Wq, Wk, Wv, msk, ws);
  hipLaunchKernelGGL(attn_fused, dim3(B), dim3(512), 0, stream,
                     src, tgt, msk, ws, out);
}